// Round 2
// baseline (183.781 us; speedup 1.0000x reference)
//
#include <hip/hip_runtime.h>
#include <hip/hip_bf16.h>

// out[bn,e] = relu(relu(hp[bn]+ep[e]+b1) @ W2 + b2) @ W3 + b3
// R6: fragment-order LDS records (conflict-free by construction) + 128-row
// blocks (halves L2 B-traffic: 1.07GB -> 537MB). 1024 thr, 16 waves, 1 blk/CU.
// 32x32x16 MFMA kept from R5; depth-2 B ping-pong + 32-slot K stagger kept.

typedef __attribute__((ext_vector_type(8))) short bf16x8;    // 8 bf16 (4 VGPR)
typedef __attribute__((ext_vector_type(16))) float f32x16;   // 32x32 MFMA acc

static __device__ __forceinline__ ushort2 pk_bf16(float a, float b) {
  union { __hip_bfloat162 h; ushort2 u; } c;
  c.h = __float22bfloat162_rn(make_float2(a, b));
  return c.u;
}
static __device__ __forceinline__ float bf2f(unsigned short u) {
  union { unsigned int i; float f; } c;
  c.i = ((unsigned int)u) << 16;
  return c.f;
}

// ---------------- fused prep (352 blocks x 256 thr) ----------------
// blocks 0..255  : hpb rows (2/blk)  hpb[r][k] = bf16(sum_h h[r][h]*W1[h][k] + b1[k])
// blocks 256..287: epb rows (8/blk)  epb[e][k] = bf16(sum_d e[e][d]*W1[256+d][k])
// blocks 288..351: w2f pack for 32x32x16 B-frags:
//   record(jg 0..15, ks 0..31): lane l holds W2[k = ks*16+(l>>5)*8+u][col = jg*32+(l&31)]
__global__ __launch_bounds__(256) void k_prep(
    const float* __restrict__ h_all, const float* __restrict__ e_feat,
    const float* __restrict__ W1, const float* __restrict__ b1,
    const float* __restrict__ W2,
    unsigned short* __restrict__ hpb, unsigned short* __restrict__ epb,
    unsigned short* __restrict__ w2f) {
  __shared__ float sm[64 * 68];   // 17408 B, reused per role
  const int t = threadIdx.x;
  const int b = blockIdx.x;

  if (b < 256) {                      // ---- hp part: 2 rows, bf16 out
    const int r0 = b * 2;
    float (*hs)[256] = (float(*)[256])sm;
    hs[0][t] = h_all[(size_t)r0 * 256 + t];
    hs[1][t] = h_all[(size_t)(r0 + 1) * 256 + t];
    __syncthreads();
    float2 a0 = make_float2(0.f, 0.f), a1 = make_float2(0.f, 0.f);
    #pragma unroll 2
    for (int k = 0; k < 256; k += 4) {
      float2 w0 = *(const float2*)(W1 + (size_t)k * 512 + 2 * t);
      float2 w1 = *(const float2*)(W1 + (size_t)(k + 1) * 512 + 2 * t);
      float2 w2v = *(const float2*)(W1 + (size_t)(k + 2) * 512 + 2 * t);
      float2 w3v = *(const float2*)(W1 + (size_t)(k + 3) * 512 + 2 * t);
      float h00 = hs[0][k], h01 = hs[0][k + 1], h02 = hs[0][k + 2], h03 = hs[0][k + 3];
      float h10 = hs[1][k], h11 = hs[1][k + 1], h12 = hs[1][k + 2], h13 = hs[1][k + 3];
      a0.x = fmaf(h00, w0.x, a0.x); a0.y = fmaf(h00, w0.y, a0.y);
      a1.x = fmaf(h10, w0.x, a1.x); a1.y = fmaf(h10, w0.y, a1.y);
      a0.x = fmaf(h01, w1.x, a0.x); a0.y = fmaf(h01, w1.y, a0.y);
      a1.x = fmaf(h11, w1.x, a1.x); a1.y = fmaf(h11, w1.y, a1.y);
      a0.x = fmaf(h02, w2v.x, a0.x); a0.y = fmaf(h02, w2v.y, a0.y);
      a1.x = fmaf(h12, w2v.x, a1.x); a1.y = fmaf(h12, w2v.y, a1.y);
      a0.x = fmaf(h03, w3v.x, a0.x); a0.y = fmaf(h03, w3v.y, a0.y);
      a1.x = fmaf(h13, w3v.x, a1.x); a1.y = fmaf(h13, w3v.y, a1.y);
    }
    float2 bv = *(const float2*)(b1 + 2 * t);
    *(ushort2*)(hpb + (size_t)r0 * 512 + 2 * t) = pk_bf16(a0.x + bv.x, a0.y + bv.y);
    *(ushort2*)(hpb + (size_t)(r0 + 1) * 512 + 2 * t) = pk_bf16(a1.x + bv.x, a1.y + bv.y);
  } else if (b < 288) {               // ---- ep part: 8 rows, bf16 out
    const int r0 = (b - 256) * 8;
    sm[t] = e_feat[(size_t)r0 * 64 + t];
    sm[256 + t] = e_feat[(size_t)r0 * 64 + 256 + t];
    __syncthreads();
    float2 acc[8];
    #pragma unroll
    for (int i = 0; i < 8; ++i) acc[i] = make_float2(0.f, 0.f);
    for (int k = 0; k < 64; ++k) {
      float2 wv = *(const float2*)(W1 + (size_t)(256 + k) * 512 + 2 * t);
      #pragma unroll
      for (int i = 0; i < 8; ++i) {
        acc[i].x = fmaf(sm[i * 64 + k], wv.x, acc[i].x);
        acc[i].y = fmaf(sm[i * 64 + k], wv.y, acc[i].y);
      }
    }
    #pragma unroll
    for (int i = 0; i < 8; ++i)
      *(ushort2*)(epb + (size_t)(r0 + i) * 512 + 2 * t) = pk_bf16(acc[i].x, acc[i].y);
  } else {                            // ---- w2f pack (32x32x16 records)
    const int bbk = b - 288;          // 0..63
    const int k0 = (bbk >> 3) * 64;
    const int c0 = (bbk & 7) * 64;
    #pragma unroll
    for (int rr = 0; rr < 4; ++rr) {
      const int row = rr * 16 + (t >> 4);
      float4 v = *(const float4*)(W2 + (size_t)(k0 + row) * 512 + c0 + (t & 15) * 4);
      *(float4*)(&sm[row * 68 + (t & 15) * 4]) = v;
    }
    __syncthreads();
    #pragma unroll
    for (int s2 = 0; s2 < 2; ++s2) {
      const int s = t * 2 + s2;       // 0..511 (8 records x 64 lanes)
      const int rec = s >> 6, l = s & 63;
      const int jg = (c0 >> 5) + (rec & 1);        // col-tile of 32
      const int ks = (k0 >> 4) + (rec >> 1);       // k-step of 16
      const int cl = (rec & 1) * 32 + (l & 31);
      const int kl = (rec >> 1) * 16 + (l >> 5) * 8;
      union { ushort2 o[4]; uint4 v; } u;
      #pragma unroll
      for (int uu = 0; uu < 4; ++uu)
        u.o[uu] = pk_bf16(sm[(kl + 2 * uu) * 68 + cl], sm[(kl + 2 * uu + 1) * 68 + cl]);
      *(uint4*)(w2f + ((size_t)(jg * 32 + ks) * 64 + l) * 8) = u.v;
    }
  }
}

// ---------------- main fused kernel ----------------
// 1024 blocks x 1024 thr (16 waves, 1 blk/CU). Block = 128 rows (one bn,
// e-half) x 512 cols. Wave w: row-half rt2 = w>>3 (64 rows), col-group
// cg = w&7 (64 cols = 2 jg). acc[2][2] f32x16 = 64 VGPR.
// LDS: x1 in A-FRAGMENT RECORD ORDER -> all ds accesses are base+lane*16,
// conflict-free by construction. record(rt 0..3, ks 0..31): slot l =
// x1[rt*32+(l&31)][ks*16+(l>>5)*8+u], u=0..7.
__global__ __launch_bounds__(1024, 4) void k_main(
    const unsigned short* __restrict__ hpb, const unsigned short* __restrict__ epb,
    const unsigned short* __restrict__ w2f, const float* __restrict__ b2,
    const float* __restrict__ W3, const float* __restrict__ b3,
    float* __restrict__ out) {
  __shared__ unsigned short x1s[128 * 512];   // 128 records x 1 KiB = 128 KiB

  const int t = threadIdx.x;
  const int lane = t & 63;
  const int w = t >> 6;            // 0..15
  const int l31 = lane & 31, l5 = lane >> 5;
  const int cg = w & 7;            // col group (64 cols)
  const int rt2 = w >> 3;          // row half (64 rows)
  const int bn = blockIdx.x >> 1;
  const int e0 = (blockIdx.x & 1) << 7;      // e-half (128 rows)
  const int off = (blockIdx.x * 7) & 31;     // K stagger (32 slots)
  const unsigned short* hprow = hpb + (size_t)bn * 512;

  // B-frag ping-pong: wave owns col-tiles jg = 2cg, 2cg+1
  const unsigned short* wrec0 = w2f + (size_t)(cg * 2) * 16384 + (size_t)lane * 8;
  const unsigned short* wrec1 = wrec0 + 16384;
  bf16x8 bb[2][2];
  bb[0][0] = *(const bf16x8*)(wrec0 + (size_t)off * 512);
  bb[0][1] = *(const bf16x8*)(wrec1 + (size_t)off * 512);
  bb[1][0] = *(const bf16x8*)(wrec0 + (size_t)((off + 1) & 31) * 512);
  bb[1][1] = *(const bf16x8*)(wrec1 + (size_t)((off + 1) & 31) * 512);

  // ---- stage x1 in record order: relu(hp + ep) -> bf16
  // wave w stages records rec = w*8 .. w*8+7; lane writes its own slot.
  {
    #pragma unroll
    for (int i = 0; i < 8; ++i) {
      const int rec = w * 8 + i;
      const int rt = rec >> 5;        // 0..3
      const int ks = rec & 31;
      const int k0 = ks * 16 + l5 * 8;
      const int er = e0 + rt * 32 + l31;
      union { uint4 v; unsigned short s[8]; } hv, ev, ov;
      hv.v = *(const uint4*)(hprow + k0);
      ev.v = *(const uint4*)(epb + (size_t)er * 512 + k0);
      #pragma unroll
      for (int u = 0; u < 4; ++u) {
        ushort2 p = pk_bf16(fmaxf(bf2f(hv.s[2 * u]) + bf2f(ev.s[2 * u]), 0.f),
                            fmaxf(bf2f(hv.s[2 * u + 1]) + bf2f(ev.s[2 * u + 1]), 0.f));
        ov.s[2 * u] = p.x;
        ov.s[2 * u + 1] = p.y;
      }
      *(uint4*)(&x1s[(size_t)rec * 512 + lane * 8]) = ov.v;
    }
  }
  __syncthreads();

  // ---- K loop: 32 steps of K=16, 4 MFMA/step; A reads are contiguous records
  const int arec0 = (rt2 * 2) * 32;      // record base for row-tile 0
  f32x16 acc[2][2] = {};
  #pragma unroll 4
  for (int ks = 0; ks < 32; ++ks) {
    const int cur = ks & 1;
    const int kr = (ks + off) & 31;
    const int kr2 = (ks + 2 + off) & 31;     // prefetch slot (wraps: dummy reload)
    bf16x8 a0 = *(const bf16x8*)(&x1s[(size_t)(arec0 + kr) * 512 + lane * 8]);
    bf16x8 a1 = *(const bf16x8*)(&x1s[(size_t)(arec0 + 32 + kr) * 512 + lane * 8]);
    acc[0][0] = __builtin_amdgcn_mfma_f32_32x32x16_bf16(a0, bb[cur][0], acc[0][0], 0, 0, 0);
    acc[1][0] = __builtin_amdgcn_mfma_f32_32x32x16_bf16(a1, bb[cur][0], acc[1][0], 0, 0, 0);
    acc[0][1] = __builtin_amdgcn_mfma_f32_32x32x16_bf16(a0, bb[cur][1], acc[0][1], 0, 0, 0);
    acc[1][1] = __builtin_amdgcn_mfma_f32_32x32x16_bf16(a1, bb[cur][1], acc[1][1], 0, 0, 0);
    bb[cur][0] = *(const bf16x8*)(wrec0 + (size_t)kr2 * 512);
    bb[cur][1] = *(const bf16x8*)(wrec1 + (size_t)kr2 * 512);
  }

  // ---- fused epilogue: osum[row] = sum_n relu(acc + b2[n]) * W3[n]
  // C layout (32x32): col = lane&31, row = (reg&3) + 8*(reg>>2) + 4*(lane>>5)
  float part[2][16];
  #pragma unroll
  for (int rt = 0; rt < 2; ++rt)
    #pragma unroll
    for (int r = 0; r < 16; ++r) part[rt][r] = 0.f;
  #pragma unroll
  for (int ct = 0; ct < 2; ++ct) {
    const int n = cg * 64 + ct * 32 + l31;
    const float b2v = b2[n], w3v = W3[n];
    #pragma unroll
    for (int rt = 0; rt < 2; ++rt)
      #pragma unroll
      for (int r = 0; r < 16; ++r)
        part[rt][r] = fmaf(fmaxf(acc[rt][ct][r] + b2v, 0.f), w3v, part[rt][r]);
  }
  #pragma unroll
  for (int rt = 0; rt < 2; ++rt)
    #pragma unroll
    for (int r = 0; r < 16; ++r) {   // reduce over the 32 col-lanes (l31)
      float v = part[rt][r];
      v += __shfl_xor(v, 1);
      v += __shfl_xor(v, 2);
      v += __shfl_xor(v, 4);
      v += __shfl_xor(v, 8);
      v += __shfl_xor(v, 16);
      part[rt][r] = v;
    }
  __syncthreads();                   // all x1s reads done before aliasing
  float* osum = (float*)x1s;         // [16 waves][64 rows-in-half]
  if (l31 == 0) {
    #pragma unroll
    for (int rt = 0; rt < 2; ++rt)
      #pragma unroll
      for (int r = 0; r < 16; ++r)
        osum[w * 64 + rt * 32 + (r & 3) + 8 * (r >> 2) + 4 * l5] = part[rt][r];
  }
  __syncthreads();
  if (t < 128) {
    const int rh = t >> 6;           // row half
    const int rl = t & 63;
    float s = b3[0];
    #pragma unroll
    for (int g = 0; g < 8; ++g) s += osum[(rh * 8 + g) * 64 + rl];
    out[(size_t)bn * 256 + e0 + t] = s;
  }
}

extern "C" void kernel_launch(void* const* d_in, const int* in_sizes, int n_in,
                              void* d_out, int out_size, void* d_ws, size_t ws_size,
                              hipStream_t stream) {
  const float* h_all  = (const float*)d_in[0];   // (8,64,256)
  const float* e_feat = (const float*)d_in[1];   // (256,64)
  const float* W1     = (const float*)d_in[2];   // (320,512)
  const float* b1     = (const float*)d_in[3];   // (512,)
  const float* W2     = (const float*)d_in[4];   // (512,512)
  const float* b2     = (const float*)d_in[5];   // (512,)
  const float* W3     = (const float*)d_in[6];   // (512,1)
  const float* b3     = (const float*)d_in[7];   // (1,)
  float* out = (float*)d_out;                    // 131072 f32

  // workspace: hpb 512KB bf16 | epb 256KB bf16 | w2f 512KB bf16
  unsigned short* hpb = (unsigned short*)d_ws;
  unsigned short* epb = hpb + 512 * 512;
  unsigned short* w2f = epb + 256 * 512;

  hipLaunchKernelGGL(k_prep, dim3(352), dim3(256), 0, stream,
                     h_all, e_feat, W1, b1, W2, hpb, epb, w2f);
  hipLaunchKernelGGL(k_main, dim3(1024), dim3(1024), 0, stream,
                     hpb, epb, w2f, b2, W3, b3, out);
}

// Round 3
// 157.252 us; speedup vs baseline: 1.1687x; 1.1687x over previous
//
#include <hip/hip_runtime.h>
#include <hip/hip_bf16.h>

// out[bn,e] = relu(relu(hp[bn]+ep[e]+b1) @ W2 + b2) @ W3 + b3
// R7 = R4 topology (64-row blocks, 256 thr, 2 blocks/CU, j-fan 8, depth-2 B
// ping-pong, K stagger) + R6's zero-conflict fragment-order LDS records
// + A register ping-pong prefetch + B reloads spread through the MFMA block.

typedef __attribute__((ext_vector_type(8))) short bf16x8;   // 8 bf16
typedef __attribute__((ext_vector_type(4))) float f32x4;    // 16x16 MFMA acc

static __device__ __forceinline__ ushort2 pk_bf16(float a, float b) {
  union { __hip_bfloat162 h; ushort2 u; } c;
  c.h = __float22bfloat162_rn(make_float2(a, b));
  return c.u;
}
static __device__ __forceinline__ float bf2f(unsigned short u) {
  union { unsigned int i; float f; } c;
  c.i = ((unsigned int)u) << 16;
  return c.f;
}

// ---------------- fused prep (352 blocks x 256 thr) ----------------
// blocks 0..255  : hpb rows (2/blk)  hpb[r][k] = bf16(sum_h h[r][h]*W1[h][k] + b1[k])
// blocks 256..287: epb rows (8/blk)  epb[e][k] = bf16(sum_d e[e][d]*W1[256+d][k])
// blocks 288..351: w2f pack (64x64 W2 tile -> bf16 B-frag records, 16x16x32)
//   record(jg,ks): lane l holds W2[k = ks*32+(l>>4)*8 + u][col = jg*16+(l&15)], u=0..7
__global__ __launch_bounds__(256) void k_prep(
    const float* __restrict__ h_all, const float* __restrict__ e_feat,
    const float* __restrict__ W1, const float* __restrict__ b1,
    const float* __restrict__ W2,
    unsigned short* __restrict__ hpb, unsigned short* __restrict__ epb,
    unsigned short* __restrict__ w2f) {
  __shared__ float sm[64 * 68];   // 17408 B, reused per role
  const int t = threadIdx.x;
  const int b = blockIdx.x;

  if (b < 256) {                      // ---- hp part: 2 rows, bf16 out
    const int r0 = b * 2;
    float (*hs)[256] = (float(*)[256])sm;
    hs[0][t] = h_all[(size_t)r0 * 256 + t];
    hs[1][t] = h_all[(size_t)(r0 + 1) * 256 + t];
    __syncthreads();
    float2 a0 = make_float2(0.f, 0.f), a1 = make_float2(0.f, 0.f);
    #pragma unroll 2
    for (int k = 0; k < 256; k += 4) {
      float2 w0 = *(const float2*)(W1 + (size_t)k * 512 + 2 * t);
      float2 w1 = *(const float2*)(W1 + (size_t)(k + 1) * 512 + 2 * t);
      float2 w2v = *(const float2*)(W1 + (size_t)(k + 2) * 512 + 2 * t);
      float2 w3v = *(const float2*)(W1 + (size_t)(k + 3) * 512 + 2 * t);
      float h00 = hs[0][k], h01 = hs[0][k + 1], h02 = hs[0][k + 2], h03 = hs[0][k + 3];
      float h10 = hs[1][k], h11 = hs[1][k + 1], h12 = hs[1][k + 2], h13 = hs[1][k + 3];
      a0.x = fmaf(h00, w0.x, a0.x); a0.y = fmaf(h00, w0.y, a0.y);
      a1.x = fmaf(h10, w0.x, a1.x); a1.y = fmaf(h10, w0.y, a1.y);
      a0.x = fmaf(h01, w1.x, a0.x); a0.y = fmaf(h01, w1.y, a0.y);
      a1.x = fmaf(h11, w1.x, a1.x); a1.y = fmaf(h11, w1.y, a1.y);
      a0.x = fmaf(h02, w2v.x, a0.x); a0.y = fmaf(h02, w2v.y, a0.y);
      a1.x = fmaf(h12, w2v.x, a1.x); a1.y = fmaf(h12, w2v.y, a1.y);
      a0.x = fmaf(h03, w3v.x, a0.x); a0.y = fmaf(h03, w3v.y, a0.y);
      a1.x = fmaf(h13, w3v.x, a1.x); a1.y = fmaf(h13, w3v.y, a1.y);
    }
    float2 bv = *(const float2*)(b1 + 2 * t);
    *(ushort2*)(hpb + (size_t)r0 * 512 + 2 * t) = pk_bf16(a0.x + bv.x, a0.y + bv.y);
    *(ushort2*)(hpb + (size_t)(r0 + 1) * 512 + 2 * t) = pk_bf16(a1.x + bv.x, a1.y + bv.y);
  } else if (b < 288) {               // ---- ep part: 8 rows, bf16 out
    const int r0 = (b - 256) * 8;
    sm[t] = e_feat[(size_t)r0 * 64 + t];
    sm[256 + t] = e_feat[(size_t)r0 * 64 + 256 + t];
    __syncthreads();
    float2 acc[8];
    #pragma unroll
    for (int i = 0; i < 8; ++i) acc[i] = make_float2(0.f, 0.f);
    for (int k = 0; k < 64; ++k) {
      float2 wv = *(const float2*)(W1 + (size_t)(256 + k) * 512 + 2 * t);
      #pragma unroll
      for (int i = 0; i < 8; ++i) {
        acc[i].x = fmaf(sm[i * 64 + k], wv.x, acc[i].x);
        acc[i].y = fmaf(sm[i * 64 + k], wv.y, acc[i].y);
      }
    }
    #pragma unroll
    for (int i = 0; i < 8; ++i)
      *(ushort2*)(epb + (size_t)(r0 + i) * 512 + 2 * t) = pk_bf16(acc[i].x, acc[i].y);
  } else {                            // ---- w2f pack
    const int bb = b - 288;           // 0..63
    const int k0 = (bb >> 3) * 64;
    const int c0 = (bb & 7) * 64;
    #pragma unroll
    for (int rr = 0; rr < 4; ++rr) {
      const int row = rr * 16 + (t >> 4);
      float4 v = *(const float4*)(W2 + (size_t)(k0 + row) * 512 + c0 + (t & 15) * 4);
      *(float4*)(&sm[row * 68 + (t & 15) * 4]) = v;
    }
    __syncthreads();
    #pragma unroll
    for (int s2 = 0; s2 < 2; ++s2) {
      const int s = t * 2 + s2;       // 0..511 (8 records x 64 lanes)
      const int rec = s >> 6, l = s & 63;
      const int jg = (c0 >> 4) + (rec & 3);
      const int ksg = (k0 >> 5) + (rec >> 2);
      const int cl = (rec & 3) * 16 + (l & 15);
      const int kl = (rec >> 2) * 32 + (l >> 4) * 8;
      union { ushort2 o[4]; uint4 v; } u;
      #pragma unroll
      for (int uu = 0; uu < 4; ++uu)
        u.o[uu] = pk_bf16(sm[(kl + 2 * uu) * 68 + cl], sm[(kl + 2 * uu + 1) * 68 + cl]);
      *(uint4*)(w2f + ((size_t)(jg * 16 + ksg) * 64 + l) * 8) = u.v;
    }
  }
}

// ---------------- main fused kernel ----------------
// 2048 blocks x 256 thr. Block = 64 rows (one bn, e-quarter) x all 512 cols.
// Wave w: cols w*128..+128 (j=0..7), rows 0..63 (i=0..3).
// x1 LDS in A-FRAGMENT RECORD ORDER: rec(rt 0..3, ks 0..15) at rec=rt*16+ks,
// slot l = x1[rt*16+(l&15)][ks*32+(l>>4)*8+u] -> all ds ops base+lane*16,
// conflict-free. A reg ping-pong af[2][4]; B reloads spread per-j.
__global__ __launch_bounds__(256, 2) void k_main(
    const unsigned short* __restrict__ hpb, const unsigned short* __restrict__ epb,
    const unsigned short* __restrict__ w2f, const float* __restrict__ b2,
    const float* __restrict__ W3, const float* __restrict__ b3,
    float* __restrict__ out) {
  __shared__ unsigned short x1s[64 * 512];   // 64 records x 1 KiB = 64 KiB

  const int t = threadIdx.x;
  const int lane = t & 63;
  const int w = t >> 6;          // 0..3 -> col group (128 cols); also staging row-tile
  const int l15 = lane & 15, l4 = lane >> 4;
  const int bn = blockIdx.x >> 2;
  const int e0 = (blockIdx.x & 3) << 6;
  const int off = (blockIdx.x * 11) & 15;   // K stagger
  const unsigned short* hprow = hpb + (size_t)bn * 512;

  // b-frag ping-pong; preload ks-slot 0 and 1 (in flight across staging)
  const unsigned short* wrec = w2f + (size_t)w * 65536 + (size_t)lane * 8;
  bf16x8 bb[2][8];
  #pragma unroll
  for (int j = 0; j < 8; ++j) {
    bb[0][j] = *(const bf16x8*)(wrec + j * 8192 + (size_t)off * 512);
    bb[1][j] = *(const bf16x8*)(wrec + j * 8192 + (size_t)((off + 1) & 15) * 512);
  }

  // ---- stage x1 in record order: wave w owns row-tile rt=w (16 rows).
  // lane l computes its own slot: row = rt*16+l15, k = ks*32+l4*8 .. +8
  {
    const unsigned short* eprow = epb + (size_t)(e0 + w * 16 + l15) * 512;
    #pragma unroll 4
    for (int ksi = 0; ksi < 16; ++ksi) {
      const int k0 = ksi * 32 + l4 * 8;
      union { uint4 v; unsigned short s[8]; } hv, ev, ov;
      hv.v = *(const uint4*)(hprow + k0);
      ev.v = *(const uint4*)(eprow + k0);
      #pragma unroll
      for (int u = 0; u < 4; ++u) {
        ushort2 p = pk_bf16(fmaxf(bf2f(hv.s[2 * u]) + bf2f(ev.s[2 * u]), 0.f),
                            fmaxf(bf2f(hv.s[2 * u + 1]) + bf2f(ev.s[2 * u + 1]), 0.f));
        ov.s[2 * u] = p.x;
        ov.s[2 * u + 1] = p.y;
      }
      *(uint4*)(&x1s[(size_t)(w * 16 + ksi) * 512 + lane * 8]) = ov.v;
    }
  }
  __syncthreads();

  // ---- A reg ping-pong: preload ks-slot `off`
  bf16x8 af[2][4];
  #pragma unroll
  for (int i = 0; i < 4; ++i)
    af[0][i] = *(const bf16x8*)(&x1s[(size_t)(i * 16 + off) * 512 + lane * 8]);

  f32x4 acc[4][8] = {};
  #pragma unroll 4
  for (int ks = 0; ks < 16; ++ks) {
    const int cur = ks & 1;
    const int nxt = cur ^ 1;
    const int kra = (ks + 1 + off) & 15;   // next A slot (wraps: dummy)
    const int krb = (ks + 2 + off) & 15;   // next-next B slot (wraps: dummy)
    #pragma unroll
    for (int j = 0; j < 8; ++j) {
      #pragma unroll
      for (int i = 0; i < 4; ++i)
        acc[i][j] = __builtin_amdgcn_mfma_f32_16x16x32_bf16(af[cur][i], bb[cur][j], acc[i][j], 0, 0, 0);
      // reload this j's B-frag for slot krb (done with bb[cur][j] now)
      bb[cur][j] = *(const bf16x8*)(wrec + j * 8192 + (size_t)krb * 512);
      // interleave next-step A prefetch among the first 4 j-blocks
      if (j < 4)
        af[nxt][j] = *(const bf16x8*)(&x1s[(size_t)(j * 16 + kra) * 512 + lane * 8]);
    }
  }

  // ---- fused epilogue: osum[row] = sum_n relu(acc + b2[n]) * W3[n]
  float part[16];
  #pragma unroll
  for (int u = 0; u < 16; ++u) part[u] = 0.f;
  #pragma unroll
  for (int j = 0; j < 8; ++j) {
    const int n = w * 128 + j * 16 + l15;
    const float b2v = b2[n], w3v = W3[n];
    #pragma unroll
    for (int i = 0; i < 4; ++i)
      #pragma unroll
      for (int r = 0; r < 4; ++r)
        part[i * 4 + r] = fmaf(fmaxf(acc[i][j][r] + b2v, 0.f), w3v, part[i * 4 + r]);
  }
  #pragma unroll
  for (int u = 0; u < 16; ++u) {     // reduce over the 16 col-lanes (l15)
    float v = part[u];
    v += __shfl_xor(v, 1);
    v += __shfl_xor(v, 2);
    v += __shfl_xor(v, 4);
    v += __shfl_xor(v, 8);
    part[u] = v;
  }
  __syncthreads();                   // all x1s reads done before aliasing
  float* osum = (float*)x1s;         // [4 col-groups][64 rows]
  if (l15 == 0) {
    #pragma unroll
    for (int i = 0; i < 4; ++i)
      #pragma unroll
      for (int r = 0; r < 4; ++r)
        osum[w * 64 + i * 16 + l4 * 4 + r] = part[i * 4 + r];
  }
  __syncthreads();
  if (t < 64) {
    float s = b3[0] + osum[t] + osum[64 + t] + osum[128 + t] + osum[192 + t];
    out[(size_t)bn * 256 + e0 + t] = s;
  }
}

extern "C" void kernel_launch(void* const* d_in, const int* in_sizes, int n_in,
                              void* d_out, int out_size, void* d_ws, size_t ws_size,
                              hipStream_t stream) {
  const float* h_all  = (const float*)d_in[0];   // (8,64,256)
  const float* e_feat = (const float*)d_in[1];   // (256,64)
  const float* W1     = (const float*)d_in[2];   // (320,512)
  const float* b1     = (const float*)d_in[3];   // (512,)
  const float* W2     = (const float*)d_in[4];   // (512,512)
  const float* b2     = (const float*)d_in[5];   // (512,)
  const float* W3     = (const float*)d_in[6];   // (512,1)
  const float* b3     = (const float*)d_in[7];   // (1,)
  float* out = (float*)d_out;                    // 131072 f32

  // workspace: hpb 512KB bf16 | epb 256KB bf16 | w2f 512KB bf16
  unsigned short* hpb = (unsigned short*)d_ws;
  unsigned short* epb = hpb + 512 * 512;
  unsigned short* w2f = epb + 256 * 512;

  hipLaunchKernelGGL(k_prep, dim3(352), dim3(256), 0, stream,
                     h_all, e_feat, W1, b1, W2, hpb, epb, w2f);
  hipLaunchKernelGGL(k_main, dim3(2048), dim3(256), 0, stream,
                     hpb, epb, w2f, b2, W3, b3, out);
}